// Round 1
// baseline (74.666 us; speedup 1.0000x reference)
//
#include <hip/hip_runtime.h>

// out[b,u] = prod_f(inputs[b,f] * weight[f,u]) + bias[u]
//          = (prod_f inputs[b,f]) * (prod_f weight[f,u]) + bias[u]
// B=32768, F=32, U=256. Pure write-bandwidth kernel after factorization.

#define F 32
#define U 256
#define ROWS_PER_BLOCK 32

__global__ __launch_bounds__(256)
void custom_neuron_kernel(const float* __restrict__ inp,
                          const float* __restrict__ weight,
                          const float* __restrict__ bias,
                          float* __restrict__ out) {
  __shared__ float pin_s[ROWS_PER_BLOCK];
  const int tid = threadIdx.x;
  const int base = blockIdx.x * ROWS_PER_BLOCK;  // first row of this chunk

  // ---- per-thread weight column-group product (redundant across 4 waves;
  //      weight is 32KB -> L1-resident, cheap) ----
  const int c = (tid & 63) * 4;  // column group 0..252
  float4 w = make_float4(1.f, 1.f, 1.f, 1.f);
#pragma unroll
  for (int f = 0; f < F; ++f) {
    const float4 wf = *(const float4*)(weight + f * U + c);
    w.x *= wf.x; w.y *= wf.y; w.z *= wf.z; w.w *= wf.w;
  }
  const float4 b = *(const float4*)(bias + c);

  // ---- row products: 32 rows x 32 floats, 8 threads per row,
  //      one fully-coalesced 4KB tile load ----
  {
    const float4 x = *(const float4*)(inp + (size_t)base * F + tid * 4);
    float p = x.x * x.y * x.z * x.w;
    p *= __shfl_xor(p, 1);
    p *= __shfl_xor(p, 2);
    p *= __shfl_xor(p, 4);
    if ((tid & 7) == 0) pin_s[tid >> 3] = p;
  }
  __syncthreads();

  // ---- epilogue: 8 x float4 stores/thread, 4 consecutive rows per step ----
  const int r0 = tid >> 6;  // 0..3
#pragma unroll
  for (int k = 0; k < 8; ++k) {
    const int row = r0 + 4 * k;
    const float p = pin_s[row];  // LDS broadcast (64 lanes same addr)
    float4 o;
    o.x = p * w.x + b.x;
    o.y = p * w.y + b.y;
    o.z = p * w.z + b.z;
    o.w = p * w.w + b.w;
    *(float4*)(out + (size_t)(base + row) * U + c) = o;
  }
}

extern "C" void kernel_launch(void* const* d_in, const int* in_sizes, int n_in,
                              void* d_out, int out_size, void* d_ws, size_t ws_size,
                              hipStream_t stream) {
  const float* inp    = (const float*)d_in[0];  // [B, F]
  const float* weight = (const float*)d_in[1];  // [F, U]
  // d_in[2] = weight_selector: dead code in the reference, unused
  const float* bias   = (const float*)d_in[3];  // [U]
  float* out = (float*)d_out;                   // [B, U]

  const int B = in_sizes[0] / F;
  const int grid = B / ROWS_PER_BLOCK;  // 1024 blocks
  custom_neuron_kernel<<<grid, 256, 0, stream>>>(inp, weight, bias, out);
}